// Round 13
// baseline (245.555 us; speedup 1.0000x reference)
//
#include <hip/hip_runtime.h>
#include <hip/hip_bf16.h>

typedef __attribute__((ext_vector_type(8))) short short8;   // 8 bf16 = 4 VGPR
typedef __attribute__((ext_vector_type(4))) float f32x4;

#define S_DIM 512
#define T_DIM 128
#define D_DIM 256
#define HD 64
#define NROWS 65536
static constexpr float LN_EPS = 1e-5f;
static constexpr float SCQ = 0.125f * 1.44269504089f;   // temp^-1 * log2(e), folded into Q

#define AS1 __attribute__((address_space(1)))
#define AS3 __attribute__((address_space(3)))

static __device__ __forceinline__ ushort f2bf(float f) {
    uint32_t b = __float_as_uint(f);
    b += 0x7FFF + ((b >> 16) & 1);   // RNE
    return (ushort)(b >> 16);
}

static __device__ __forceinline__ uint cvtpk(float lo, float hi) {
    uint r;
    asm("v_cvt_pk_bf16_f32 %0, %1, %2" : "=v"(r) : "v"(lo), "v"(hi));
    return r;
}

// ---------------------------------------------------------------------------
// LayerNorm fp32 -> bf16. One wave per 256-row; 4 rows per block.
// ---------------------------------------------------------------------------
__global__ __launch_bounds__(256) void ln_bf16(const float* __restrict__ x,
                                               const float* __restrict__ g,
                                               const float* __restrict__ b,
                                               ushort* __restrict__ out) {
    int row = blockIdx.x * 4 + (threadIdx.x >> 6);
    int lane = threadIdx.x & 63;
    size_t base = (size_t)row * D_DIM + lane * 4;
    float4 xv = *reinterpret_cast<const float4*>(x + base);
    float s = xv.x + xv.y + xv.z + xv.w;
    float q = xv.x * xv.x + xv.y * xv.y + xv.z * xv.z + xv.w * xv.w;
#pragma unroll
    for (int off = 32; off > 0; off >>= 1) {
        s += __shfl_xor(s, off);
        q += __shfl_xor(q, off);
    }
    float mu = s * (1.0f / D_DIM);
    float var = q * (1.0f / D_DIM) - mu * mu;
    float rstd = rsqrtf(var + LN_EPS);
    float4 gv = *reinterpret_cast<const float4*>(g + lane * 4);
    float4 bv = *reinterpret_cast<const float4*>(b + lane * 4);
    ushort4 o = make_ushort4(f2bf((xv.x - mu) * rstd * gv.x + bv.x),
                             f2bf((xv.y - mu) * rstd * gv.y + bv.y),
                             f2bf((xv.z - mu) * rstd * gv.z + bv.z),
                             f2bf((xv.w - mu) * rstd * gv.w + bv.w));
    *reinterpret_cast<ushort4*>(out + base) = o;
}

// ---------------------------------------------------------------------------
// Weight conversion fp32 -> bf16 (5 x 256x256)
// ---------------------------------------------------------------------------
__global__ __launch_bounds__(256) void wconv(const float* __restrict__ w0, const float* __restrict__ w1,
                                             const float* __restrict__ w2, const float* __restrict__ w3,
                                             const float* __restrict__ w4, ushort* __restrict__ dst) {
    const float* s;
    switch (blockIdx.y) {
        case 0: s = w0; break;
        case 1: s = w1; break;
        case 2: s = w2; break;
        case 3: s = w3; break;
        default: s = w4; break;
    }
    int idx = (blockIdx.x * 256 + threadIdx.x) * 4;
    float4 v = *reinterpret_cast<const float4*>(s + idx);
    ushort4 o = make_ushort4(f2bf(v.x), f2bf(v.y), f2bf(v.z), f2bf(v.w));
    *reinterpret_cast<ushort4*>(dst + (size_t)blockIdx.y * 65536 + idx) = o;
}

// ---------------------------------------------------------------------------
// bf16 MFMA GEMM, m97-style global_load_lds staging (linear LDS dest +
// inverse-swizzled global source, rule #21), single-buffered, 2 barriers/step.
// BM=BN=128, BK=64, 256 thr (4 waves, 64x64 out each).
// M_QKV: fused Q/K/V projection. Grid (512, 6). M_H / M_FFN2: FFN layers.
// ---------------------------------------------------------------------------
enum { M_QKV = 0, M_H = 1, M_FFN2 = 2 };

template <int MODE>
__global__ __launch_bounds__(256) void gemm_m97(const ushort* __restrict__ A,
                                                const ushort* __restrict__ Wall,
                                                const float* __restrict__ bias,
                                                const float* __restrict__ res,
                                                void* __restrict__ outp) {
    __shared__ uint4 As[1024];   // 128 rows x 8 chunks of 16B
    __shared__ uint4 Bs[1024];
    const int tid = threadIdx.x;
    const int lane = tid & 63;
    const int wid = tid >> 6;
    const int y = blockIdx.y;
    const int wm = (wid >> 1) * 64;
    const int wn = (wid & 1) * 64;

    constexpr bool QKV = (MODE == M_QKV);
    const int tblk = blockIdx.x >> 2;          // QKV: fixed t per block
    const int s0 = (blockIdx.x & 3) * 128;     // QKV: s-panel
    const int m0 = blockIdx.x * 128;

    const ushort* Abase = QKV ? A + ((size_t)s0 * T_DIM + tblk) * D_DIM
                              : A + (size_t)m0 * D_DIM;
    const size_t Ast = QKV ? (size_t)T_DIM * D_DIM : (size_t)D_DIM;
    const int n0 = QKV ? (y & 1) * 128 : y * 128;
    const ushort* Wbase = (QKV ? Wall + (size_t)(y >> 1) * 65536 : Wall) + (size_t)n0 * D_DIM;

    f32x4 acc[4][4];
#pragma unroll
    for (int mi = 0; mi < 4; ++mi)
#pragma unroll
        for (int ni = 0; ni < 4; ++ni) acc[mi][ni] = (f32x4){0.f, 0.f, 0.f, 0.f};

    const int srow = tid >> 3;   // 0..31 per iter-block
    const int sc = tid & 7;

    for (int ks = 0; ks < 4; ++ks) {
        const int k0 = ks * 64;
#pragma unroll
        for (int it = 0; it < 4; ++it) {
            int row = it * 32 + srow;
            int c = sc ^ (row & 7);
            __builtin_amdgcn_global_load_lds(
                (const AS1 void*)(Abase + (size_t)row * Ast + k0 + c * 8),
                (AS3 void*)&As[it * 256 + wid * 64], 16, 0, 0);
            __builtin_amdgcn_global_load_lds(
                (const AS1 void*)(Wbase + (size_t)row * D_DIM + k0 + c * 8),
                (AS3 void*)&Bs[it * 256 + wid * 64], 16, 0, 0);
        }
        __syncthreads();   // drain vmcnt: tile resident
#pragma unroll
        for (int kk = 0; kk < 2; ++kk) {
            short8 af[4], bf[4];
#pragma unroll
            for (int mi = 0; mi < 4; ++mi) {
                int row = wm + mi * 16 + (lane & 15);
                int c = kk * 4 + (lane >> 4);
                af[mi] = *reinterpret_cast<const short8*>(&As[row * 8 + (c ^ (row & 7))]);
            }
#pragma unroll
            for (int ni = 0; ni < 4; ++ni) {
                int row = wn + ni * 16 + (lane & 15);
                int c = kk * 4 + (lane >> 4);
                bf[ni] = *reinterpret_cast<const short8*>(&Bs[row * 8 + (c ^ (row & 7))]);
            }
#pragma unroll
            for (int mi = 0; mi < 4; ++mi)
#pragma unroll
                for (int ni = 0; ni < 4; ++ni)
                    acc[mi][ni] = __builtin_amdgcn_mfma_f32_16x16x32_bf16(af[mi], bf[ni], acc[mi][ni], 0, 0, 0);
        }
        __syncthreads();   // all reads done before next stage overwrites
    }

    // Epilogue. D layout: row=(lane>>4)*4+r, col=lane&15 (m89).
    if (MODE == M_QKV) {
        ushort* outb = (ushort*)outp + (size_t)(y >> 1) * 16777216;
        const bool isV = (y >= 4);
        const float scale = (y < 2) ? SCQ : 1.0f;
#pragma unroll
        for (int mi = 0; mi < 4; ++mi) {
#pragma unroll
            for (int ni = 0; ni < 4; ++ni) {
                int gn = n0 + wn + ni * 16 + (lane & 15);
                if (isV) {
                    // pi^-1(s): bits[4:3]=s[3:2], bit[2]=s[4]; bits 1:0 kept
                    int s = s0 + wm + mi * 16 + (lane >> 4) * 4;
                    int p = (s & ~28) | ((s & 12) << 1) | ((s & 16) >> 2);
                    ushort4 o = make_ushort4(f2bf(acc[mi][ni][0]), f2bf(acc[mi][ni][1]),
                                             f2bf(acc[mi][ni][2]), f2bf(acc[mi][ni][3]));
                    *reinterpret_cast<ushort4*>(
                        &outb[((size_t)tblk * D_DIM + gn) * S_DIM + p]) = o;
                } else {
#pragma unroll
                    for (int r = 0; r < 4; ++r) {
                        int s = s0 + wm + mi * 16 + (lane >> 4) * 4 + r;
                        outb[(size_t)tblk * (S_DIM * D_DIM) + (size_t)s * D_DIM + gn] =
                            f2bf(acc[mi][ni][r] * scale);
                    }
                }
            }
        }
    } else {
#pragma unroll
        for (int mi = 0; mi < 4; ++mi) {
#pragma unroll
            for (int ni = 0; ni < 4; ++ni) {
                int gn = n0 + wn + ni * 16 + (lane & 15);
#pragma unroll
                for (int r = 0; r < 4; ++r) {
                    int gm = m0 + wm + mi * 16 + (lane >> 4) * 4 + r;
                    float v = acc[mi][ni][r];
                    if (MODE == M_H) {
                        v += bias[gn];
                        v = fmaxf(v, 0.f);
                        ((ushort*)outp)[(size_t)gm * D_DIM + gn] = f2bf(v);
                    } else {
                        v += bias[gn] + res[(size_t)gm * D_DIM + gn];
                        ((float*)outp)[(size_t)gm * D_DIM + gn] = v;
                    }
                }
            }
        }
    }
}

// ---------------------------------------------------------------------------
// MFMA flash attention, in-register softmax, 3-buffer counted-vmcnt pipeline
// (T3/T4): prefetch distance 2, s_waitcnt vmcnt(4) + raw s_barrier per tile —
// never drains to 0 in steady state, so each tile's loads get a full
// iteration in flight. vmcnt algebra: per-thread 4 loads/STAGE; at each
// barrier outstanding = {tile jt+1: 4, tile jt+2: 4}; vmcnt(4) retires tile
// jt+1 exactly. Buffer written at iter jt is buf(jt-1)%3, whose readers all
// passed the previous barrier. setprio(1) wraps MFMA clusters (T5).
// ---------------------------------------------------------------------------
__global__ __launch_bounds__(256) void attn_mfma(const ushort* __restrict__ qb,
                                                 const ushort* __restrict__ kb,
                                                 const ushort* __restrict__ vtb,
                                                 const float* __restrict__ x,
                                                 float* __restrict__ xt) {
    __shared__ uint4 Ks[3][512];
    __shared__ uint4 Vs[3][512];
    const int tid = threadIdx.x;
    const int lane = tid & 63;
    const int wid = tid >> 6;
    const int t = blockIdx.x;
    const int h = blockIdx.z;
    const int i0 = blockIdx.y * 64 + wid * 16;

    short8 qf[2];
    {
        const ushort* qrow = qb + ((size_t)t * S_DIM + i0 + (lane & 15)) * D_DIM + h * HD;
#pragma unroll
        for (int kk = 0; kk < 2; ++kk)
            qf[kk] = *reinterpret_cast<const short8*>(qrow + kk * 32 + (lane >> 4) * 8);
    }

    f32x4 oacc[4];
#pragma unroll
    for (int dt = 0; dt < 4; ++dt) oacc[dt] = (f32x4){0.f, 0.f, 0.f, 0.f};
    float psl = 0.f;

    const ushort* kbase = kb + (size_t)t * (S_DIM * D_DIM) + h * HD;
    const ushort* vbase = vtb + ((size_t)t * D_DIM + h * HD) * S_DIM;

#define STAGE(buf, j0)                                                                      \
    {                                                                                       \
        _Pragma("unroll") for (int it = 0; it < 2; ++it) {                                  \
            int slot = wid * 128 + it * 64 + lane;                                          \
            int row = slot >> 3;                                                            \
            int c = (slot & 7) ^ (row & 7);                                                 \
            __builtin_amdgcn_global_load_lds(                                               \
                (const AS1 void*)(kbase + (size_t)((j0) + row) * D_DIM + c * 8),            \
                (AS3 void*)&Ks[buf][wid * 128 + it * 64], 16, 0, 0);                        \
            __builtin_amdgcn_global_load_lds(                                               \
                (const AS1 void*)(vbase + (size_t)row * S_DIM + (j0) + c * 8),              \
                (AS3 void*)&Vs[buf][wid * 128 + it * 64], 16, 0, 0);                        \
        }                                                                                   \
    }
#define WAITV4 { asm volatile("s_waitcnt vmcnt(4)" ::: "memory"); __builtin_amdgcn_sched_barrier(0); }
#define WAITV0 { asm volatile("s_waitcnt vmcnt(0)" ::: "memory"); __builtin_amdgcn_sched_barrier(0); }

    STAGE(0, 0)
    STAGE(1, 64)
    WAITV4                                   // tile 0 resident; tile 1 in flight
    __builtin_amdgcn_s_barrier();
    int cs = 0;                              // buffer holding tile jt

    for (int jt = 0; jt < 8; ++jt) {
        if (jt < 6) {
            int nb = (cs == 0) ? 2 : cs - 1; // (cs+2)%3
            STAGE(nb, (jt + 2) * 64)
        }

        f32x4 sacc[4];
#pragma unroll
        for (int ct = 0; ct < 4; ++ct) sacc[ct] = (f32x4){0.f, 0.f, 0.f, 0.f};
        __builtin_amdgcn_s_setprio(1);
#pragma unroll
        for (int kk = 0; kk < 2; ++kk) {
#pragma unroll
            for (int ct = 0; ct < 4; ++ct) {
                int row = ct * 16 + (lane & 15);
                int c = kk * 4 + (lane >> 4);
                short8 kf = *reinterpret_cast<const short8*>(&Ks[cs][row * 8 + (c ^ (row & 7))]);
                sacc[ct] = __builtin_amdgcn_mfma_f32_16x16x32_bf16(kf, qf[kk], sacc[ct], 0, 0, 0);
            }
        }
        __builtin_amdgcn_s_setprio(0);

        // P = exp2(S) (Q pre-scaled); pack pairs bf16x2, all lane-local
        uint pk[4][2];
#pragma unroll
        for (int ct = 0; ct < 4; ++ct) {
            float p0 = exp2f(sacc[ct][0]);
            float p1 = exp2f(sacc[ct][1]);
            float p2 = exp2f(sacc[ct][2]);
            float p3 = exp2f(sacc[ct][3]);
            psl += (p0 + p1) + (p2 + p3);
            pk[ct][0] = cvtpk(p0, p1);
            pk[ct][1] = cvtpk(p2, p3);
        }

        // O += P V : A-frag lane-local under pi (V^T pre-permuted)
        __builtin_amdgcn_s_setprio(1);
#pragma unroll
        for (int jh = 0; jh < 2; ++jh) {
            int4 pd;
            pd.x = (int)pk[2 * jh][0];
            pd.y = (int)pk[2 * jh][1];
            pd.z = (int)pk[2 * jh + 1][0];
            pd.w = (int)pk[2 * jh + 1][1];
            short8 pf = *reinterpret_cast<short8*>(&pd);
            int c = jh * 4 + (lane >> 4);
#pragma unroll
            for (int dt = 0; dt < 4; ++dt) {
                int row = dt * 16 + (lane & 15);
                short8 vf = *reinterpret_cast<const short8*>(&Vs[cs][row * 8 + (c ^ (row & 7))]);
                oacc[dt] = __builtin_amdgcn_mfma_f32_16x16x32_bf16(pf, vf, oacc[dt], 0, 0, 0);
            }
        }
        __builtin_amdgcn_s_setprio(0);

        if (jt < 7) {
            if (jt < 6) { WAITV4 }           // retire tile jt+1; keep jt+2 flying
            else        { WAITV0 }           // last staged tile (7): full drain
            __builtin_amdgcn_s_barrier();
            cs = (cs == 2) ? 0 : cs + 1;
        }
    }
#undef STAGE
#undef WAITV4
#undef WAITV0

    // Row sums: lanes {l, l^16, l^32, l^48} share row i=lane&15
    psl += __shfl_xor(psl, 16);
    psl += __shfl_xor(psl, 32);
    float inv = 1.0f / psl;
    float invr[4];
#pragma unroll
    for (int r = 0; r < 4; ++r)
        invr[r] = __int_as_float(__builtin_amdgcn_ds_bpermute(
            (((lane >> 4) * 4 + r) << 2), __float_as_int(inv)));

#pragma unroll
    for (int dt = 0; dt < 4; ++dt) {
#pragma unroll
        for (int r = 0; r < 4; ++r) {
            int srow = i0 + (lane >> 4) * 4 + r;
            size_t oidx = (size_t)srow * (T_DIM * D_DIM) + (size_t)t * D_DIM + h * HD + dt * 16 + (lane & 15);
            xt[oidx] = x[oidx] + oacc[dt][r] * invr[r];
        }
    }
}

// ---------------------------------------------------------------------------
extern "C" void kernel_launch(void* const* d_in, const int* in_sizes, int n_in,
                              void* d_out, int out_size, void* d_ws, size_t ws_size,
                              hipStream_t stream) {
    const float* x  = (const float*)d_in[0];
    const float* wq = (const float*)d_in[1];
    const float* wk = (const float*)d_in[2];
    const float* wv = (const float*)d_in[3];
    const float* g1 = (const float*)d_in[4];
    const float* be1 = (const float*)d_in[5];
    const float* g2 = (const float*)d_in[6];
    const float* be2 = (const float*)d_in[7];
    const float* w1 = (const float*)d_in[8];
    const float* b1 = (const float*)d_in[9];
    const float* w2 = (const float*)d_in[10];
    const float* b2 = (const float*)d_in[11];
    float* out = (float*)d_out;

    char* ws = (char*)d_ws;
    const size_t MB = 1024ull * 1024;
    ushort* xnb = (ushort*)ws;                // 32 MB: LN1 out, later LN2 out
    ushort* qb  = (ushort*)(ws + 32 * MB);    // 32 MB: Q [T,S,D] (pre-scaled); later FFN hidden
    ushort* kb  = (ushort*)(ws + 64 * MB);    // 32 MB: K [T,S,D]
    ushort* vtb = (ushort*)(ws + 96 * MB);    // 32 MB: V^T [T,D,S] (pi-permuted s)
    ushort* wb  = (ushort*)(ws + 128 * MB);   // 5 x 64K bf16 weights (wq,wk,wv,w1,w2)
    ushort* w1b = wb + 3 * 65536;
    ushort* w2b = wb + 4 * 65536;
    ushort* hb  = qb;

    wconv<<<dim3(64, 5), 256, 0, stream>>>(wq, wk, wv, w1, w2, wb);
    ln_bf16<<<NROWS / 4, 256, 0, stream>>>(x, g1, be1, xnb);
    gemm_m97<M_QKV><<<dim3(512, 6), 256, 0, stream>>>(xnb, wb, nullptr, nullptr, qb);
    attn_mfma<<<dim3(T_DIM, S_DIM / 64, 4), 256, 0, stream>>>(qb, kb, vtb, x, out);
    ln_bf16<<<NROWS / 4, 256, 0, stream>>>(out, g2, be2, xnb);
    gemm_m97<M_H><<<dim3(512, 2), 256, 0, stream>>>(xnb, w1b, b1, nullptr, hb);
    gemm_m97<M_FFN2><<<dim3(512, 2), 256, 0, stream>>>(hb, w2b, b2, out, out);
}

// Round 14
// 239.645 us; speedup vs baseline: 1.0247x; 1.0247x over previous
//
#include <hip/hip_runtime.h>
#include <hip/hip_bf16.h>

typedef __attribute__((ext_vector_type(8))) short short8;   // 8 bf16 = 4 VGPR
typedef __attribute__((ext_vector_type(4))) float f32x4;

#define S_DIM 512
#define T_DIM 128
#define D_DIM 256
#define HD 64
#define NROWS 65536
static constexpr float LN_EPS = 1e-5f;
static constexpr float SCQ = 0.125f * 1.44269504089f;   // temp^-1 * log2(e), folded into Q

#define AS1 __attribute__((address_space(1)))
#define AS3 __attribute__((address_space(3)))

static __device__ __forceinline__ ushort f2bf(float f) {
    uint32_t b = __float_as_uint(f);
    b += 0x7FFF + ((b >> 16) & 1);   // RNE
    return (ushort)(b >> 16);
}

static __device__ __forceinline__ uint cvtpk(float lo, float hi) {
    uint r;
    asm("v_cvt_pk_bf16_f32 %0, %1, %2" : "=v"(r) : "v"(lo), "v"(hi));
    return r;
}

// ---------------------------------------------------------------------------
// LayerNorm fp32 -> bf16. One wave per 256-row; 4 rows per block.
// ---------------------------------------------------------------------------
__global__ __launch_bounds__(256) void ln_bf16(const float* __restrict__ x,
                                               const float* __restrict__ g,
                                               const float* __restrict__ b,
                                               ushort* __restrict__ out) {
    int row = blockIdx.x * 4 + (threadIdx.x >> 6);
    int lane = threadIdx.x & 63;
    size_t base = (size_t)row * D_DIM + lane * 4;
    float4 xv = *reinterpret_cast<const float4*>(x + base);
    float s = xv.x + xv.y + xv.z + xv.w;
    float q = xv.x * xv.x + xv.y * xv.y + xv.z * xv.z + xv.w * xv.w;
#pragma unroll
    for (int off = 32; off > 0; off >>= 1) {
        s += __shfl_xor(s, off);
        q += __shfl_xor(q, off);
    }
    float mu = s * (1.0f / D_DIM);
    float var = q * (1.0f / D_DIM) - mu * mu;
    float rstd = rsqrtf(var + LN_EPS);
    float4 gv = *reinterpret_cast<const float4*>(g + lane * 4);
    float4 bv = *reinterpret_cast<const float4*>(b + lane * 4);
    ushort4 o = make_ushort4(f2bf((xv.x - mu) * rstd * gv.x + bv.x),
                             f2bf((xv.y - mu) * rstd * gv.y + bv.y),
                             f2bf((xv.z - mu) * rstd * gv.z + bv.z),
                             f2bf((xv.w - mu) * rstd * gv.w + bv.w));
    *reinterpret_cast<ushort4*>(out + base) = o;
}

// ---------------------------------------------------------------------------
// Weight conversion fp32 -> bf16 (5 x 256x256)
// ---------------------------------------------------------------------------
__global__ __launch_bounds__(256) void wconv(const float* __restrict__ w0, const float* __restrict__ w1,
                                             const float* __restrict__ w2, const float* __restrict__ w3,
                                             const float* __restrict__ w4, ushort* __restrict__ dst) {
    const float* s;
    switch (blockIdx.y) {
        case 0: s = w0; break;
        case 1: s = w1; break;
        case 2: s = w2; break;
        case 3: s = w3; break;
        default: s = w4; break;
    }
    int idx = (blockIdx.x * 256 + threadIdx.x) * 4;
    float4 v = *reinterpret_cast<const float4*>(s + idx);
    ushort4 o = make_ushort4(f2bf(v.x), f2bf(v.y), f2bf(v.z), f2bf(v.w));
    *reinterpret_cast<ushort4*>(dst + (size_t)blockIdx.y * 65536 + idx) = o;
}

// ---------------------------------------------------------------------------
// bf16 MFMA GEMM, m97-style global_load_lds staging (linear LDS dest +
// inverse-swizzled global source, rule #21), single-buffered, 2 barriers/step.
// BM=BN=128, BK=64, 256 thr (4 waves, 64x64 out each).
// M_QKV: fused Q/K/V projection. Grid (512, 6). M_H / M_FFN2: FFN layers.
// ---------------------------------------------------------------------------
enum { M_QKV = 0, M_H = 1, M_FFN2 = 2 };

template <int MODE>
__global__ __launch_bounds__(256) void gemm_m97(const ushort* __restrict__ A,
                                                const ushort* __restrict__ Wall,
                                                const float* __restrict__ bias,
                                                const float* __restrict__ res,
                                                void* __restrict__ outp) {
    __shared__ uint4 As[1024];   // 128 rows x 8 chunks of 16B
    __shared__ uint4 Bs[1024];
    const int tid = threadIdx.x;
    const int lane = tid & 63;
    const int wid = tid >> 6;
    const int y = blockIdx.y;
    const int wm = (wid >> 1) * 64;
    const int wn = (wid & 1) * 64;

    constexpr bool QKV = (MODE == M_QKV);
    const int tblk = blockIdx.x >> 2;          // QKV: fixed t per block
    const int s0 = (blockIdx.x & 3) * 128;     // QKV: s-panel
    const int m0 = blockIdx.x * 128;

    const ushort* Abase = QKV ? A + ((size_t)s0 * T_DIM + tblk) * D_DIM
                              : A + (size_t)m0 * D_DIM;
    const size_t Ast = QKV ? (size_t)T_DIM * D_DIM : (size_t)D_DIM;
    const int n0 = QKV ? (y & 1) * 128 : y * 128;
    const ushort* Wbase = (QKV ? Wall + (size_t)(y >> 1) * 65536 : Wall) + (size_t)n0 * D_DIM;

    f32x4 acc[4][4];
#pragma unroll
    for (int mi = 0; mi < 4; ++mi)
#pragma unroll
        for (int ni = 0; ni < 4; ++ni) acc[mi][ni] = (f32x4){0.f, 0.f, 0.f, 0.f};

    const int srow = tid >> 3;   // 0..31 per iter-block
    const int sc = tid & 7;

    for (int ks = 0; ks < 4; ++ks) {
        const int k0 = ks * 64;
#pragma unroll
        for (int it = 0; it < 4; ++it) {
            int row = it * 32 + srow;
            int c = sc ^ (row & 7);
            __builtin_amdgcn_global_load_lds(
                (const AS1 void*)(Abase + (size_t)row * Ast + k0 + c * 8),
                (AS3 void*)&As[it * 256 + wid * 64], 16, 0, 0);
            __builtin_amdgcn_global_load_lds(
                (const AS1 void*)(Wbase + (size_t)row * D_DIM + k0 + c * 8),
                (AS3 void*)&Bs[it * 256 + wid * 64], 16, 0, 0);
        }
        __syncthreads();   // drain vmcnt: tile resident
#pragma unroll
        for (int kk = 0; kk < 2; ++kk) {
            short8 af[4], bf[4];
#pragma unroll
            for (int mi = 0; mi < 4; ++mi) {
                int row = wm + mi * 16 + (lane & 15);
                int c = kk * 4 + (lane >> 4);
                af[mi] = *reinterpret_cast<const short8*>(&As[row * 8 + (c ^ (row & 7))]);
            }
#pragma unroll
            for (int ni = 0; ni < 4; ++ni) {
                int row = wn + ni * 16 + (lane & 15);
                int c = kk * 4 + (lane >> 4);
                bf[ni] = *reinterpret_cast<const short8*>(&Bs[row * 8 + (c ^ (row & 7))]);
            }
#pragma unroll
            for (int mi = 0; mi < 4; ++mi)
#pragma unroll
                for (int ni = 0; ni < 4; ++ni)
                    acc[mi][ni] = __builtin_amdgcn_mfma_f32_16x16x32_bf16(af[mi], bf[ni], acc[mi][ni], 0, 0, 0);
        }
        __syncthreads();   // all reads done before next stage overwrites
    }

    // Epilogue. D layout: row=(lane>>4)*4+r, col=lane&15 (m89).
    if (MODE == M_QKV) {
        ushort* outb = (ushort*)outp + (size_t)(y >> 1) * 16777216;
        const bool isV = (y >= 4);
        const float scale = (y < 2) ? SCQ : 1.0f;
#pragma unroll
        for (int mi = 0; mi < 4; ++mi) {
#pragma unroll
            for (int ni = 0; ni < 4; ++ni) {
                int gn = n0 + wn + ni * 16 + (lane & 15);
                if (isV) {
                    // pi^-1(s): bits[4:3]=s[3:2], bit[2]=s[4]; bits 1:0 kept
                    int s = s0 + wm + mi * 16 + (lane >> 4) * 4;
                    int p = (s & ~28) | ((s & 12) << 1) | ((s & 16) >> 2);
                    ushort4 o = make_ushort4(f2bf(acc[mi][ni][0]), f2bf(acc[mi][ni][1]),
                                             f2bf(acc[mi][ni][2]), f2bf(acc[mi][ni][3]));
                    *reinterpret_cast<ushort4*>(
                        &outb[((size_t)tblk * D_DIM + gn) * S_DIM + p]) = o;
                } else {
#pragma unroll
                    for (int r = 0; r < 4; ++r) {
                        int s = s0 + wm + mi * 16 + (lane >> 4) * 4 + r;
                        outb[(size_t)tblk * (S_DIM * D_DIM) + (size_t)s * D_DIM + gn] =
                            f2bf(acc[mi][ni][r] * scale);
                    }
                }
            }
        }
    } else {
#pragma unroll
        for (int mi = 0; mi < 4; ++mi) {
#pragma unroll
            for (int ni = 0; ni < 4; ++ni) {
                int gn = n0 + wn + ni * 16 + (lane & 15);
#pragma unroll
                for (int r = 0; r < 4; ++r) {
                    int gm = m0 + wm + mi * 16 + (lane >> 4) * 4 + r;
                    float v = acc[mi][ni][r];
                    if (MODE == M_H) {
                        v += bias[gn];
                        v = fmaxf(v, 0.f);
                        ((ushort*)outp)[(size_t)gm * D_DIM + gn] = f2bf(v);
                    } else {
                        v += bias[gn] + res[(size_t)gm * D_DIM + gn];
                        ((float*)outp)[(size_t)gm * D_DIM + gn] = v;
                    }
                }
            }
        }
    }
}

// ---------------------------------------------------------------------------
// MFMA flash attention, in-register softmax, 32 q-rows per wave (two row
// groups A/B sharing every K/V fragment load: mfma(kf,qfA)+mfma(kf,qfB)).
// Halves LDS reads, staging address calc, and barriers per FLOP; group B's
// QK MFMAs overlap group A's softmax VALU chain (in-wave ILP, T15 mechanism).
// Round-12 sync structure (2 buffers, __syncthreads, runtime jt loop) — the
// counted-vmcnt 3-buffer pipeline regressed twice (VGPR 88, occ 20.7%).
// Grid (x=t, y=i-chunk of 128, z=h): all blocks of one t share an XCD.
// Q pre-scaled by SCQ -> exp2f direct. PV A-frag lane-local via pi-permuted
// V^T storage. K/V staged via global_load_lds (rule #21).
// ---------------------------------------------------------------------------
__global__ __launch_bounds__(256) void attn_mfma(const ushort* __restrict__ qb,
                                                 const ushort* __restrict__ kb,
                                                 const ushort* __restrict__ vtb,
                                                 const float* __restrict__ x,
                                                 float* __restrict__ xt) {
    __shared__ uint4 Ks[2][512];
    __shared__ uint4 Vs[2][512];
    const int tid = threadIdx.x;
    const int lane = tid & 63;
    const int wid = tid >> 6;
    const int t = blockIdx.x;
    const int h = blockIdx.z;
    const int i0 = blockIdx.y * 128 + wid * 32;   // 32 rows per wave

    short8 qfA[2], qfB[2];
    {
        const ushort* qrowA = qb + ((size_t)t * S_DIM + i0 + (lane & 15)) * D_DIM + h * HD;
        const ushort* qrowB = qrowA + 16 * D_DIM;
#pragma unroll
        for (int kk = 0; kk < 2; ++kk) {
            qfA[kk] = *reinterpret_cast<const short8*>(qrowA + kk * 32 + (lane >> 4) * 8);
            qfB[kk] = *reinterpret_cast<const short8*>(qrowB + kk * 32 + (lane >> 4) * 8);
        }
    }

    f32x4 oaccA[4], oaccB[4];
#pragma unroll
    for (int dt = 0; dt < 4; ++dt) {
        oaccA[dt] = (f32x4){0.f, 0.f, 0.f, 0.f};
        oaccB[dt] = (f32x4){0.f, 0.f, 0.f, 0.f};
    }
    float pslA = 0.f, pslB = 0.f;

    const ushort* kbase = kb + (size_t)t * (S_DIM * D_DIM) + h * HD;
    const ushort* vbase = vtb + ((size_t)t * D_DIM + h * HD) * S_DIM;

#define STAGE(buf, j0)                                                                      \
    {                                                                                       \
        _Pragma("unroll") for (int it = 0; it < 2; ++it) {                                  \
            int slot = wid * 128 + it * 64 + lane;                                          \
            int row = slot >> 3;                                                            \
            int c = (slot & 7) ^ (row & 7);                                                 \
            __builtin_amdgcn_global_load_lds(                                               \
                (const AS1 void*)(kbase + (size_t)((j0) + row) * D_DIM + c * 8),            \
                (AS3 void*)&Ks[buf][wid * 128 + it * 64], 16, 0, 0);                        \
            __builtin_amdgcn_global_load_lds(                                               \
                (const AS1 void*)(vbase + (size_t)row * S_DIM + (j0) + c * 8),              \
                (AS3 void*)&Vs[buf][wid * 128 + it * 64], 16, 0, 0);                        \
        }                                                                                   \
    }

    STAGE(0, 0)
    __syncthreads();
    int cur = 0;

    for (int jt = 0; jt < 8; ++jt) {
        if (jt < 7) STAGE(cur ^ 1, (jt + 1) * 64)

        f32x4 saccA[4], saccB[4];
#pragma unroll
        for (int ct = 0; ct < 4; ++ct) {
            saccA[ct] = (f32x4){0.f, 0.f, 0.f, 0.f};
            saccB[ct] = (f32x4){0.f, 0.f, 0.f, 0.f};
        }
#pragma unroll
        for (int kk = 0; kk < 2; ++kk) {
#pragma unroll
            for (int ct = 0; ct < 4; ++ct) {
                int row = ct * 16 + (lane & 15);
                int c = kk * 4 + (lane >> 4);
                short8 kf = *reinterpret_cast<const short8*>(&Ks[cur][row * 8 + (c ^ (row & 7))]);
                saccA[ct] = __builtin_amdgcn_mfma_f32_16x16x32_bf16(kf, qfA[kk], saccA[ct], 0, 0, 0);
                saccB[ct] = __builtin_amdgcn_mfma_f32_16x16x32_bf16(kf, qfB[kk], saccB[ct], 0, 0, 0);
            }
        }

        // P = exp2(S) (Q pre-scaled); pack pairs bf16x2, all lane-local
        uint pkA[4][2], pkB[4][2];
#pragma unroll
        for (int ct = 0; ct < 4; ++ct) {
            float a0 = exp2f(saccA[ct][0]);
            float a1 = exp2f(saccA[ct][1]);
            float a2 = exp2f(saccA[ct][2]);
            float a3 = exp2f(saccA[ct][3]);
            pslA += (a0 + a1) + (a2 + a3);
            pkA[ct][0] = cvtpk(a0, a1);
            pkA[ct][1] = cvtpk(a2, a3);
            float b0 = exp2f(saccB[ct][0]);
            float b1 = exp2f(saccB[ct][1]);
            float b2 = exp2f(saccB[ct][2]);
            float b3 = exp2f(saccB[ct][3]);
            pslB += (b0 + b1) + (b2 + b3);
            pkB[ct][0] = cvtpk(b0, b1);
            pkB[ct][1] = cvtpk(b2, b3);
        }

        // O += P V : A-frags lane-local under pi; vf shared across groups
#pragma unroll
        for (int jh = 0; jh < 2; ++jh) {
            int4 pda, pdb;
            pda.x = (int)pkA[2 * jh][0];
            pda.y = (int)pkA[2 * jh][1];
            pda.z = (int)pkA[2 * jh + 1][0];
            pda.w = (int)pkA[2 * jh + 1][1];
            pdb.x = (int)pkB[2 * jh][0];
            pdb.y = (int)pkB[2 * jh][1];
            pdb.z = (int)pkB[2 * jh + 1][0];
            pdb.w = (int)pkB[2 * jh + 1][1];
            short8 pfA = *reinterpret_cast<short8*>(&pda);
            short8 pfB = *reinterpret_cast<short8*>(&pdb);
            int c = jh * 4 + (lane >> 4);
#pragma unroll
            for (int dt = 0; dt < 4; ++dt) {
                int row = dt * 16 + (lane & 15);
                short8 vf = *reinterpret_cast<const short8*>(&Vs[cur][row * 8 + (c ^ (row & 7))]);
                oaccA[dt] = __builtin_amdgcn_mfma_f32_16x16x32_bf16(pfA, vf, oaccA[dt], 0, 0, 0);
                oaccB[dt] = __builtin_amdgcn_mfma_f32_16x16x32_bf16(pfB, vf, oaccB[dt], 0, 0, 0);
            }
        }

        if (jt < 7) {
            __syncthreads();
            cur ^= 1;
        }
    }
#undef STAGE

    // Row sums: lanes {l, l^16, l^32, l^48} share row i=lane&15
    pslA += __shfl_xor(pslA, 16);
    pslA += __shfl_xor(pslA, 32);
    pslB += __shfl_xor(pslB, 16);
    pslB += __shfl_xor(pslB, 32);
    float invA = 1.0f / pslA;
    float invB = 1.0f / pslB;
    float invrA[4], invrB[4];
#pragma unroll
    for (int r = 0; r < 4; ++r) {
        int a = ((lane >> 4) * 4 + r) << 2;
        invrA[r] = __int_as_float(__builtin_amdgcn_ds_bpermute(a, __float_as_int(invA)));
        invrB[r] = __int_as_float(__builtin_amdgcn_ds_bpermute(a, __float_as_int(invB)));
    }

#pragma unroll
    for (int dt = 0; dt < 4; ++dt) {
#pragma unroll
        for (int r = 0; r < 4; ++r) {
            int srowA = i0 + (lane >> 4) * 4 + r;
            size_t oidx = (size_t)srowA * (T_DIM * D_DIM) + (size_t)t * D_DIM + h * HD + dt * 16 + (lane & 15);
            xt[oidx] = x[oidx] + oaccA[dt][r] * invrA[r];
            size_t oidxB = oidx + (size_t)16 * (T_DIM * D_DIM);
            xt[oidxB] = x[oidxB] + oaccB[dt][r] * invrB[r];
        }
    }
}

// ---------------------------------------------------------------------------
extern "C" void kernel_launch(void* const* d_in, const int* in_sizes, int n_in,
                              void* d_out, int out_size, void* d_ws, size_t ws_size,
                              hipStream_t stream) {
    const float* x  = (const float*)d_in[0];
    const float* wq = (const float*)d_in[1];
    const float* wk = (const float*)d_in[2];
    const float* wv = (const float*)d_in[3];
    const float* g1 = (const float*)d_in[4];
    const float* be1 = (const float*)d_in[5];
    const float* g2 = (const float*)d_in[6];
    const float* be2 = (const float*)d_in[7];
    const float* w1 = (const float*)d_in[8];
    const float* b1 = (const float*)d_in[9];
    const float* w2 = (const float*)d_in[10];
    const float* b2 = (const float*)d_in[11];
    float* out = (float*)d_out;

    char* ws = (char*)d_ws;
    const size_t MB = 1024ull * 1024;
    ushort* xnb = (ushort*)ws;                // 32 MB: LN1 out, later LN2 out
    ushort* qb  = (ushort*)(ws + 32 * MB);    // 32 MB: Q [T,S,D] (pre-scaled); later FFN hidden
    ushort* kb  = (ushort*)(ws + 64 * MB);    // 32 MB: K [T,S,D]
    ushort* vtb = (ushort*)(ws + 96 * MB);    // 32 MB: V^T [T,D,S] (pi-permuted s)
    ushort* wb  = (ushort*)(ws + 128 * MB);   // 5 x 64K bf16 weights (wq,wk,wv,w1,w2)
    ushort* w1b = wb + 3 * 65536;
    ushort* w2b = wb + 4 * 65536;
    ushort* hb  = qb;

    wconv<<<dim3(64, 5), 256, 0, stream>>>(wq, wk, wv, w1, w2, wb);
    ln_bf16<<<NROWS / 4, 256, 0, stream>>>(x, g1, be1, xnb);
    gemm_m97<M_QKV><<<dim3(512, 6), 256, 0, stream>>>(xnb, wb, nullptr, nullptr, qb);
    attn_mfma<<<dim3(T_DIM, S_DIM / 128, 4), 256, 0, stream>>>(qb, kb, vtb, x, out);
    ln_bf16<<<NROWS / 4, 256, 0, stream>>>(out, g2, be2, xnb);
    gemm_m97<M_H><<<dim3(512, 2), 256, 0, stream>>>(xnb, w1b, b1, nullptr, hb);
    gemm_m97<M_FFN2><<<dim3(512, 2), 256, 0, stream>>>(hb, w2b, b2, out, out);
}

// Round 15
// 228.163 us; speedup vs baseline: 1.0762x; 1.0503x over previous
//
#include <hip/hip_runtime.h>
#include <hip/hip_bf16.h>

typedef __attribute__((ext_vector_type(8))) short short8;   // 8 bf16 = 4 VGPR
typedef __attribute__((ext_vector_type(4))) float f32x4;

#define S_DIM 512
#define T_DIM 128
#define D_DIM 256
#define HD 64
#define NROWS 65536
static constexpr float LN_EPS = 1e-5f;
static constexpr float SCQ = 0.125f * 1.44269504089f;   // temp^-1 * log2(e), folded into Q

#define AS1 __attribute__((address_space(1)))
#define AS3 __attribute__((address_space(3)))

static __device__ __forceinline__ ushort f2bf(float f) {
    uint32_t b = __float_as_uint(f);
    b += 0x7FFF + ((b >> 16) & 1);   // RNE
    return (ushort)(b >> 16);
}

static __device__ __forceinline__ uint cvtpk(float lo, float hi) {
    uint r;
    asm("v_cvt_pk_bf16_f32 %0, %1, %2" : "=v"(r) : "v"(lo), "v"(hi));
    return r;
}

// raw hardware 2^x (v_exp_f32). exp2f() is the libm __ocml path with
// edge-case handling — measurably slower in the attn hot chain (r10 vs r12).
static __device__ __forceinline__ float ex2(float x) {
    float r;
    asm("v_exp_f32 %0, %1" : "=v"(r) : "v"(x));
    return r;
}

// ---------------------------------------------------------------------------
// LayerNorm fp32 -> bf16. One wave per 256-row; 4 rows per block.
// ---------------------------------------------------------------------------
__global__ __launch_bounds__(256) void ln_bf16(const float* __restrict__ x,
                                               const float* __restrict__ g,
                                               const float* __restrict__ b,
                                               ushort* __restrict__ out) {
    int row = blockIdx.x * 4 + (threadIdx.x >> 6);
    int lane = threadIdx.x & 63;
    size_t base = (size_t)row * D_DIM + lane * 4;
    float4 xv = *reinterpret_cast<const float4*>(x + base);
    float s = xv.x + xv.y + xv.z + xv.w;
    float q = xv.x * xv.x + xv.y * xv.y + xv.z * xv.z + xv.w * xv.w;
#pragma unroll
    for (int off = 32; off > 0; off >>= 1) {
        s += __shfl_xor(s, off);
        q += __shfl_xor(q, off);
    }
    float mu = s * (1.0f / D_DIM);
    float var = q * (1.0f / D_DIM) - mu * mu;
    float rstd = rsqrtf(var + LN_EPS);
    float4 gv = *reinterpret_cast<const float4*>(g + lane * 4);
    float4 bv = *reinterpret_cast<const float4*>(b + lane * 4);
    ushort4 o = make_ushort4(f2bf((xv.x - mu) * rstd * gv.x + bv.x),
                             f2bf((xv.y - mu) * rstd * gv.y + bv.y),
                             f2bf((xv.z - mu) * rstd * gv.z + bv.z),
                             f2bf((xv.w - mu) * rstd * gv.w + bv.w));
    *reinterpret_cast<ushort4*>(out + base) = o;
}

// ---------------------------------------------------------------------------
// Weight conversion fp32 -> bf16 (5 x 256x256)
// ---------------------------------------------------------------------------
__global__ __launch_bounds__(256) void wconv(const float* __restrict__ w0, const float* __restrict__ w1,
                                             const float* __restrict__ w2, const float* __restrict__ w3,
                                             const float* __restrict__ w4, ushort* __restrict__ dst) {
    const float* s;
    switch (blockIdx.y) {
        case 0: s = w0; break;
        case 1: s = w1; break;
        case 2: s = w2; break;
        case 3: s = w3; break;
        default: s = w4; break;
    }
    int idx = (blockIdx.x * 256 + threadIdx.x) * 4;
    float4 v = *reinterpret_cast<const float4*>(s + idx);
    ushort4 o = make_ushort4(f2bf(v.x), f2bf(v.y), f2bf(v.z), f2bf(v.w));
    *reinterpret_cast<ushort4*>(dst + (size_t)blockIdx.y * 65536 + idx) = o;
}

// ---------------------------------------------------------------------------
// bf16 MFMA GEMM, m97-style global_load_lds staging (linear LDS dest +
// inverse-swizzled global source, rule #21), single-buffered, 2 barriers/step.
// BM=BN=128, BK=64, 256 thr (4 waves, 64x64 out each).
// M_QKV: fused Q/K/V projection. Grid (512, 6). M_H / M_FFN2: FFN layers.
// ---------------------------------------------------------------------------
enum { M_QKV = 0, M_H = 1, M_FFN2 = 2 };

template <int MODE>
__global__ __launch_bounds__(256) void gemm_m97(const ushort* __restrict__ A,
                                                const ushort* __restrict__ Wall,
                                                const float* __restrict__ bias,
                                                const float* __restrict__ res,
                                                void* __restrict__ outp) {
    __shared__ uint4 As[1024];   // 128 rows x 8 chunks of 16B
    __shared__ uint4 Bs[1024];
    const int tid = threadIdx.x;
    const int lane = tid & 63;
    const int wid = tid >> 6;
    const int y = blockIdx.y;
    const int wm = (wid >> 1) * 64;
    const int wn = (wid & 1) * 64;

    constexpr bool QKV = (MODE == M_QKV);
    const int tblk = blockIdx.x >> 2;          // QKV: fixed t per block
    const int s0 = (blockIdx.x & 3) * 128;     // QKV: s-panel
    const int m0 = blockIdx.x * 128;

    const ushort* Abase = QKV ? A + ((size_t)s0 * T_DIM + tblk) * D_DIM
                              : A + (size_t)m0 * D_DIM;
    const size_t Ast = QKV ? (size_t)T_DIM * D_DIM : (size_t)D_DIM;
    const int n0 = QKV ? (y & 1) * 128 : y * 128;
    const ushort* Wbase = (QKV ? Wall + (size_t)(y >> 1) * 65536 : Wall) + (size_t)n0 * D_DIM;

    f32x4 acc[4][4];
#pragma unroll
    for (int mi = 0; mi < 4; ++mi)
#pragma unroll
        for (int ni = 0; ni < 4; ++ni) acc[mi][ni] = (f32x4){0.f, 0.f, 0.f, 0.f};

    const int srow = tid >> 3;   // 0..31 per iter-block
    const int sc = tid & 7;

    for (int ks = 0; ks < 4; ++ks) {
        const int k0 = ks * 64;
#pragma unroll
        for (int it = 0; it < 4; ++it) {
            int row = it * 32 + srow;
            int c = sc ^ (row & 7);
            __builtin_amdgcn_global_load_lds(
                (const AS1 void*)(Abase + (size_t)row * Ast + k0 + c * 8),
                (AS3 void*)&As[it * 256 + wid * 64], 16, 0, 0);
            __builtin_amdgcn_global_load_lds(
                (const AS1 void*)(Wbase + (size_t)row * D_DIM + k0 + c * 8),
                (AS3 void*)&Bs[it * 256 + wid * 64], 16, 0, 0);
        }
        __syncthreads();   // drain vmcnt: tile resident
#pragma unroll
        for (int kk = 0; kk < 2; ++kk) {
            short8 af[4], bf[4];
#pragma unroll
            for (int mi = 0; mi < 4; ++mi) {
                int row = wm + mi * 16 + (lane & 15);
                int c = kk * 4 + (lane >> 4);
                af[mi] = *reinterpret_cast<const short8*>(&As[row * 8 + (c ^ (row & 7))]);
            }
#pragma unroll
            for (int ni = 0; ni < 4; ++ni) {
                int row = wn + ni * 16 + (lane & 15);
                int c = kk * 4 + (lane >> 4);
                bf[ni] = *reinterpret_cast<const short8*>(&Bs[row * 8 + (c ^ (row & 7))]);
            }
#pragma unroll
            for (int mi = 0; mi < 4; ++mi)
#pragma unroll
                for (int ni = 0; ni < 4; ++ni)
                    acc[mi][ni] = __builtin_amdgcn_mfma_f32_16x16x32_bf16(af[mi], bf[ni], acc[mi][ni], 0, 0, 0);
        }
        __syncthreads();   // all reads done before next stage overwrites
    }

    // Epilogue. D layout: row=(lane>>4)*4+r, col=lane&15 (m89).
    if (MODE == M_QKV) {
        ushort* outb = (ushort*)outp + (size_t)(y >> 1) * 16777216;
        const bool isV = (y >= 4);
        const float scale = (y < 2) ? SCQ : 1.0f;
#pragma unroll
        for (int mi = 0; mi < 4; ++mi) {
#pragma unroll
            for (int ni = 0; ni < 4; ++ni) {
                int gn = n0 + wn + ni * 16 + (lane & 15);
                if (isV) {
                    // pi^-1(s): bits[4:3]=s[3:2], bit[2]=s[4]; bits 1:0 kept
                    int s = s0 + wm + mi * 16 + (lane >> 4) * 4;
                    int p = (s & ~28) | ((s & 12) << 1) | ((s & 16) >> 2);
                    ushort4 o = make_ushort4(f2bf(acc[mi][ni][0]), f2bf(acc[mi][ni][1]),
                                             f2bf(acc[mi][ni][2]), f2bf(acc[mi][ni][3]));
                    *reinterpret_cast<ushort4*>(
                        &outb[((size_t)tblk * D_DIM + gn) * S_DIM + p]) = o;
                } else {
#pragma unroll
                    for (int r = 0; r < 4; ++r) {
                        int s = s0 + wm + mi * 16 + (lane >> 4) * 4 + r;
                        outb[(size_t)tblk * (S_DIM * D_DIM) + (size_t)s * D_DIM + gn] =
                            f2bf(acc[mi][ni][r] * scale);
                    }
                }
            }
        }
    } else {
#pragma unroll
        for (int mi = 0; mi < 4; ++mi) {
#pragma unroll
            for (int ni = 0; ni < 4; ++ni) {
                int gn = n0 + wn + ni * 16 + (lane & 15);
#pragma unroll
                for (int r = 0; r < 4; ++r) {
                    int gm = m0 + wm + mi * 16 + (lane >> 4) * 4 + r;
                    float v = acc[mi][ni][r];
                    if (MODE == M_H) {
                        v += bias[gn];
                        v = fmaxf(v, 0.f);
                        ((ushort*)outp)[(size_t)gm * D_DIM + gn] = f2bf(v);
                    } else {
                        v += bias[gn] + res[(size_t)gm * D_DIM + gn];
                        ((float*)outp)[(size_t)gm * D_DIM + gn] = v;
                    }
                }
            }
        }
    }
}

// ---------------------------------------------------------------------------
// MFMA flash attention, in-register softmax, 32 q-rows per wave (two row
// groups A/B sharing every K/V fragment load). Round-12 sync structure
// (2 buffers, __syncthreads, runtime jt loop). P = 2^S via raw v_exp_f32
// (ex2) — libm exp2f was the r11/r12 attn regression.
// Grid (x=t, y=i-chunk of 128, z=h): all blocks of one t share an XCD.
// PV A-frag lane-local via pi-permuted V^T storage. K/V staged via
// global_load_lds (linear dest + inverse-swizzled global source, rule #21).
// ---------------------------------------------------------------------------
__global__ __launch_bounds__(256) void attn_mfma(const ushort* __restrict__ qb,
                                                 const ushort* __restrict__ kb,
                                                 const ushort* __restrict__ vtb,
                                                 const float* __restrict__ x,
                                                 float* __restrict__ xt) {
    __shared__ uint4 Ks[2][512];
    __shared__ uint4 Vs[2][512];
    const int tid = threadIdx.x;
    const int lane = tid & 63;
    const int wid = tid >> 6;
    const int t = blockIdx.x;
    const int h = blockIdx.z;
    const int i0 = blockIdx.y * 128 + wid * 32;   // 32 rows per wave

    short8 qfA[2], qfB[2];
    {
        const ushort* qrowA = qb + ((size_t)t * S_DIM + i0 + (lane & 15)) * D_DIM + h * HD;
        const ushort* qrowB = qrowA + 16 * D_DIM;
#pragma unroll
        for (int kk = 0; kk < 2; ++kk) {
            qfA[kk] = *reinterpret_cast<const short8*>(qrowA + kk * 32 + (lane >> 4) * 8);
            qfB[kk] = *reinterpret_cast<const short8*>(qrowB + kk * 32 + (lane >> 4) * 8);
        }
    }

    f32x4 oaccA[4], oaccB[4];
#pragma unroll
    for (int dt = 0; dt < 4; ++dt) {
        oaccA[dt] = (f32x4){0.f, 0.f, 0.f, 0.f};
        oaccB[dt] = (f32x4){0.f, 0.f, 0.f, 0.f};
    }
    float pslA = 0.f, pslB = 0.f;

    const ushort* kbase = kb + (size_t)t * (S_DIM * D_DIM) + h * HD;
    const ushort* vbase = vtb + ((size_t)t * D_DIM + h * HD) * S_DIM;

#define STAGE(buf, j0)                                                                      \
    {                                                                                       \
        _Pragma("unroll") for (int it = 0; it < 2; ++it) {                                  \
            int slot = wid * 128 + it * 64 + lane;                                          \
            int row = slot >> 3;                                                            \
            int c = (slot & 7) ^ (row & 7);                                                 \
            __builtin_amdgcn_global_load_lds(                                               \
                (const AS1 void*)(kbase + (size_t)((j0) + row) * D_DIM + c * 8),            \
                (AS3 void*)&Ks[buf][wid * 128 + it * 64], 16, 0, 0);                        \
            __builtin_amdgcn_global_load_lds(                                               \
                (const AS1 void*)(vbase + (size_t)row * S_DIM + (j0) + c * 8),              \
                (AS3 void*)&Vs[buf][wid * 128 + it * 64], 16, 0, 0);                        \
        }                                                                                   \
    }

    STAGE(0, 0)
    __syncthreads();
    int cur = 0;

    for (int jt = 0; jt < 8; ++jt) {
        if (jt < 7) STAGE(cur ^ 1, (jt + 1) * 64)

        f32x4 saccA[4], saccB[4];
#pragma unroll
        for (int ct = 0; ct < 4; ++ct) {
            saccA[ct] = (f32x4){0.f, 0.f, 0.f, 0.f};
            saccB[ct] = (f32x4){0.f, 0.f, 0.f, 0.f};
        }
#pragma unroll
        for (int kk = 0; kk < 2; ++kk) {
#pragma unroll
            for (int ct = 0; ct < 4; ++ct) {
                int row = ct * 16 + (lane & 15);
                int c = kk * 4 + (lane >> 4);
                short8 kf = *reinterpret_cast<const short8*>(&Ks[cur][row * 8 + (c ^ (row & 7))]);
                saccA[ct] = __builtin_amdgcn_mfma_f32_16x16x32_bf16(kf, qfA[kk], saccA[ct], 0, 0, 0);
                saccB[ct] = __builtin_amdgcn_mfma_f32_16x16x32_bf16(kf, qfB[kk], saccB[ct], 0, 0, 0);
            }
        }

        // P = 2^S (Q pre-scaled); pack pairs bf16x2, all lane-local
        uint pkA[4][2], pkB[4][2];
#pragma unroll
        for (int ct = 0; ct < 4; ++ct) {
            float a0 = ex2(saccA[ct][0]);
            float a1 = ex2(saccA[ct][1]);
            float a2 = ex2(saccA[ct][2]);
            float a3 = ex2(saccA[ct][3]);
            pslA += (a0 + a1) + (a2 + a3);
            pkA[ct][0] = cvtpk(a0, a1);
            pkA[ct][1] = cvtpk(a2, a3);
            float b0 = ex2(saccB[ct][0]);
            float b1 = ex2(saccB[ct][1]);
            float b2 = ex2(saccB[ct][2]);
            float b3 = ex2(saccB[ct][3]);
            pslB += (b0 + b1) + (b2 + b3);
            pkB[ct][0] = cvtpk(b0, b1);
            pkB[ct][1] = cvtpk(b2, b3);
        }

        // O += P V : A-frags lane-local under pi; vf shared across groups
#pragma unroll
        for (int jh = 0; jh < 2; ++jh) {
            int4 pda, pdb;
            pda.x = (int)pkA[2 * jh][0];
            pda.y = (int)pkA[2 * jh][1];
            pda.z = (int)pkA[2 * jh + 1][0];
            pda.w = (int)pkA[2 * jh + 1][1];
            pdb.x = (int)pkB[2 * jh][0];
            pdb.y = (int)pkB[2 * jh][1];
            pdb.z = (int)pkB[2 * jh + 1][0];
            pdb.w = (int)pkB[2 * jh + 1][1];
            short8 pfA = *reinterpret_cast<short8*>(&pda);
            short8 pfB = *reinterpret_cast<short8*>(&pdb);
            int c = jh * 4 + (lane >> 4);
#pragma unroll
            for (int dt = 0; dt < 4; ++dt) {
                int row = dt * 16 + (lane & 15);
                short8 vf = *reinterpret_cast<const short8*>(&Vs[cur][row * 8 + (c ^ (row & 7))]);
                oaccA[dt] = __builtin_amdgcn_mfma_f32_16x16x32_bf16(pfA, vf, oaccA[dt], 0, 0, 0);
                oaccB[dt] = __builtin_amdgcn_mfma_f32_16x16x32_bf16(pfB, vf, oaccB[dt], 0, 0, 0);
            }
        }

        if (jt < 7) {
            __syncthreads();
            cur ^= 1;
        }
    }
#undef STAGE

    // Row sums: lanes {l, l^16, l^32, l^48} share row i=lane&15
    pslA += __shfl_xor(pslA, 16);
    pslA += __shfl_xor(pslA, 32);
    pslB += __shfl_xor(pslB, 16);
    pslB += __shfl_xor(pslB, 32);
    float invA = 1.0f / pslA;
    float invB = 1.0f / pslB;
    float invrA[4], invrB[4];
#pragma unroll
    for (int r = 0; r < 4; ++r) {
        int a = ((lane >> 4) * 4 + r) << 2;
        invrA[r] = __int_as_float(__builtin_amdgcn_ds_bpermute(a, __float_as_int(invA)));
        invrB[r] = __int_as_float(__builtin_amdgcn_ds_bpermute(a, __float_as_int(invB)));
    }

#pragma unroll
    for (int dt = 0; dt < 4; ++dt) {
#pragma unroll
        for (int r = 0; r < 4; ++r) {
            int srowA = i0 + (lane >> 4) * 4 + r;
            size_t oidx = (size_t)srowA * (T_DIM * D_DIM) + (size_t)t * D_DIM + h * HD + dt * 16 + (lane & 15);
            xt[oidx] = x[oidx] + oaccA[dt][r] * invrA[r];
            size_t oidxB = oidx + (size_t)16 * (T_DIM * D_DIM);
            xt[oidxB] = x[oidxB] + oaccB[dt][r] * invrB[r];
        }
    }
}

// ---------------------------------------------------------------------------
extern "C" void kernel_launch(void* const* d_in, const int* in_sizes, int n_in,
                              void* d_out, int out_size, void* d_ws, size_t ws_size,
                              hipStream_t stream) {
    const float* x  = (const float*)d_in[0];
    const float* wq = (const float*)d_in[1];
    const float* wk = (const float*)d_in[2];
    const float* wv = (const float*)d_in[3];
    const float* g1 = (const float*)d_in[4];
    const float* be1 = (const float*)d_in[5];
    const float* g2 = (const float*)d_in[6];
    const float* be2 = (const float*)d_in[7];
    const float* w1 = (const float*)d_in[8];
    const float* b1 = (const float*)d_in[9];
    const float* w2 = (const float*)d_in[10];
    const float* b2 = (const float*)d_in[11];
    float* out = (float*)d_out;

    char* ws = (char*)d_ws;
    const size_t MB = 1024ull * 1024;
    ushort* xnb = (ushort*)ws;                // 32 MB: LN1 out, later LN2 out
    ushort* qb  = (ushort*)(ws + 32 * MB);    // 32 MB: Q [T,S,D] (pre-scaled); later FFN hidden
    ushort* kb  = (ushort*)(ws + 64 * MB);    // 32 MB: K [T,S,D]
    ushort* vtb = (ushort*)(ws + 96 * MB);    // 32 MB: V^T [T,D,S] (pi-permuted s)
    ushort* wb  = (ushort*)(ws + 128 * MB);   // 5 x 64K bf16 weights (wq,wk,wv,w1,w2)
    ushort* w1b = wb + 3 * 65536;
    ushort* w2b = wb + 4 * 65536;
    ushort* hb  = qb;

    wconv<<<dim3(64, 5), 256, 0, stream>>>(wq, wk, wv, w1, w2, wb);
    ln_bf16<<<NROWS / 4, 256, 0, stream>>>(x, g1, be1, xnb);
    gemm_m97<M_QKV><<<dim3(512, 6), 256, 0, stream>>>(xnb, wb, nullptr, nullptr, qb);
    attn_mfma<<<dim3(T_DIM, S_DIM / 128, 4), 256, 0, stream>>>(qb, kb, vtb, x, out);
    ln_bf16<<<NROWS / 4, 256, 0, stream>>>(out, g2, be2, xnb);
    gemm_m97<M_H><<<dim3(512, 2), 256, 0, stream>>>(xnb, w1b, b1, nullptr, hb);
    gemm_m97<M_FFN2><<<dim3(512, 2), 256, 0, stream>>>(hb, w2b, b2, out, out);
}

// Round 16
// 226.250 us; speedup vs baseline: 1.0853x; 1.0085x over previous
//
#include <hip/hip_runtime.h>
#include <hip/hip_bf16.h>

typedef __attribute__((ext_vector_type(8))) short short8;   // 8 bf16 = 4 VGPR
typedef __attribute__((ext_vector_type(4))) float f32x4;

#define S_DIM 512
#define T_DIM 128
#define D_DIM 256
#define HD 64
#define NROWS 65536
static constexpr float LN_EPS = 1e-5f;
static constexpr float SCQ = 0.125f * 1.44269504089f;   // temp^-1 * log2(e), folded into Q

#define AS1 __attribute__((address_space(1)))
#define AS3 __attribute__((address_space(3)))

static __device__ __forceinline__ ushort f2bf(float f) {
    uint32_t b = __float_as_uint(f);
    b += 0x7FFF + ((b >> 16) & 1);   // RNE
    return (ushort)(b >> 16);
}

static __device__ __forceinline__ uint cvtpk(float lo, float hi) {
    uint r;
    asm("v_cvt_pk_bf16_f32 %0, %1, %2" : "=v"(r) : "v"(lo), "v"(hi));
    return r;
}

// raw hardware 2^x (v_exp_f32). exp2f() is the libm __ocml path with
// edge-case handling — measurably slower in the attn hot chain (r10 vs r12).
static __device__ __forceinline__ float ex2(float x) {
    float r;
    asm("v_exp_f32 %0, %1" : "=v"(r) : "v"(x));
    return r;
}

// ---------------------------------------------------------------------------
// LayerNorm fp32 -> bf16. One wave per 256-row; 4 rows per block.
// ---------------------------------------------------------------------------
__global__ __launch_bounds__(256) void ln_bf16(const float* __restrict__ x,
                                               const float* __restrict__ g,
                                               const float* __restrict__ b,
                                               ushort* __restrict__ out) {
    int row = blockIdx.x * 4 + (threadIdx.x >> 6);
    int lane = threadIdx.x & 63;
    size_t base = (size_t)row * D_DIM + lane * 4;
    float4 xv = *reinterpret_cast<const float4*>(x + base);
    float s = xv.x + xv.y + xv.z + xv.w;
    float q = xv.x * xv.x + xv.y * xv.y + xv.z * xv.z + xv.w * xv.w;
#pragma unroll
    for (int off = 32; off > 0; off >>= 1) {
        s += __shfl_xor(s, off);
        q += __shfl_xor(q, off);
    }
    float mu = s * (1.0f / D_DIM);
    float var = q * (1.0f / D_DIM) - mu * mu;
    float rstd = rsqrtf(var + LN_EPS);
    float4 gv = *reinterpret_cast<const float4*>(g + lane * 4);
    float4 bv = *reinterpret_cast<const float4*>(b + lane * 4);
    ushort4 o = make_ushort4(f2bf((xv.x - mu) * rstd * gv.x + bv.x),
                             f2bf((xv.y - mu) * rstd * gv.y + bv.y),
                             f2bf((xv.z - mu) * rstd * gv.z + bv.z),
                             f2bf((xv.w - mu) * rstd * gv.w + bv.w));
    *reinterpret_cast<ushort4*>(out + base) = o;
}

// ---------------------------------------------------------------------------
// Weight conversion fp32 -> bf16 (5 x 256x256)
// ---------------------------------------------------------------------------
__global__ __launch_bounds__(256) void wconv(const float* __restrict__ w0, const float* __restrict__ w1,
                                             const float* __restrict__ w2, const float* __restrict__ w3,
                                             const float* __restrict__ w4, ushort* __restrict__ dst) {
    const float* s;
    switch (blockIdx.y) {
        case 0: s = w0; break;
        case 1: s = w1; break;
        case 2: s = w2; break;
        case 3: s = w3; break;
        default: s = w4; break;
    }
    int idx = (blockIdx.x * 256 + threadIdx.x) * 4;
    float4 v = *reinterpret_cast<const float4*>(s + idx);
    ushort4 o = make_ushort4(f2bf(v.x), f2bf(v.y), f2bf(v.z), f2bf(v.w));
    *reinterpret_cast<ushort4*>(dst + (size_t)blockIdx.y * 65536 + idx) = o;
}

// ---------------------------------------------------------------------------
// bf16 MFMA GEMM, DOUBLE-BUFFERED global_load_lds staging (T3 2-phase):
// STAGE(next tile) issued BEFORE computing current tile; single __syncthreads
// per K-step (drains vmcnt + protects buffer reuse) — loads fly under MFMA.
// (Previous version staged then immediately drained: load latency fully
// exposed; at K=256 only 4 steps amortized it -> ~500 TF.)
// LDS: 2 x (As 16KB + Bs 16KB) = 64KB -> 2 blocks/CU.
// BM=BN=128, BK=64, 256 thr (4 waves, 64x64 out each). Rule #21: linear LDS
// dest + inverse-swizzled global source, swizzled read side.
// M_QKV: fused Q/K/V projection, grid (512, 6). M_H / M_FFN2: FFN layers.
// ---------------------------------------------------------------------------
enum { M_QKV = 0, M_H = 1, M_FFN2 = 2 };

template <int MODE>
__global__ __launch_bounds__(256) void gemm_m97(const ushort* __restrict__ A,
                                                const ushort* __restrict__ Wall,
                                                const float* __restrict__ bias,
                                                const float* __restrict__ res,
                                                void* __restrict__ outp) {
    __shared__ uint4 As[2][1024];   // 128 rows x 8 chunks of 16B, double-buffered
    __shared__ uint4 Bs[2][1024];
    const int tid = threadIdx.x;
    const int lane = tid & 63;
    const int wid = tid >> 6;
    const int y = blockIdx.y;
    const int wm = (wid >> 1) * 64;
    const int wn = (wid & 1) * 64;

    constexpr bool QKV = (MODE == M_QKV);
    const int tblk = blockIdx.x >> 2;          // QKV: fixed t per block
    const int s0 = (blockIdx.x & 3) * 128;     // QKV: s-panel
    const int m0 = blockIdx.x * 128;

    const ushort* Abase = QKV ? A + ((size_t)s0 * T_DIM + tblk) * D_DIM
                              : A + (size_t)m0 * D_DIM;
    const size_t Ast = QKV ? (size_t)T_DIM * D_DIM : (size_t)D_DIM;
    const int n0 = QKV ? (y & 1) * 128 : y * 128;
    const ushort* Wbase = (QKV ? Wall + (size_t)(y >> 1) * 65536 : Wall) + (size_t)n0 * D_DIM;

    f32x4 acc[4][4];
#pragma unroll
    for (int mi = 0; mi < 4; ++mi)
#pragma unroll
        for (int ni = 0; ni < 4; ++ni) acc[mi][ni] = (f32x4){0.f, 0.f, 0.f, 0.f};

    const int srow = tid >> 3;   // 0..31 per iter-block
    const int sc = tid & 7;

#define GSTAGE(buf, k0)                                                                     \
    {                                                                                       \
        _Pragma("unroll") for (int it = 0; it < 4; ++it) {                                  \
            int row = it * 32 + srow;                                                       \
            int c = sc ^ (row & 7);                                                         \
            __builtin_amdgcn_global_load_lds(                                               \
                (const AS1 void*)(Abase + (size_t)row * Ast + (k0) + c * 8),                \
                (AS3 void*)&As[buf][it * 256 + wid * 64], 16, 0, 0);                        \
            __builtin_amdgcn_global_load_lds(                                               \
                (const AS1 void*)(Wbase + (size_t)row * D_DIM + (k0) + c * 8),              \
                (AS3 void*)&Bs[buf][it * 256 + wid * 64], 16, 0, 0);                        \
        }                                                                                   \
    }

    GSTAGE(0, 0)
    __syncthreads();   // tile 0 resident
    int cur = 0;

    for (int ks = 0; ks < 4; ++ks) {
        if (ks < 3) GSTAGE(cur ^ 1, (ks + 1) * 64)   // loads fly under MFMA
#pragma unroll
        for (int kk = 0; kk < 2; ++kk) {
            short8 af[4], bf[4];
#pragma unroll
            for (int mi = 0; mi < 4; ++mi) {
                int row = wm + mi * 16 + (lane & 15);
                int c = kk * 4 + (lane >> 4);
                af[mi] = *reinterpret_cast<const short8*>(&As[cur][row * 8 + (c ^ (row & 7))]);
            }
#pragma unroll
            for (int ni = 0; ni < 4; ++ni) {
                int row = wn + ni * 16 + (lane & 15);
                int c = kk * 4 + (lane >> 4);
                bf[ni] = *reinterpret_cast<const short8*>(&Bs[cur][row * 8 + (c ^ (row & 7))]);
            }
#pragma unroll
            for (int mi = 0; mi < 4; ++mi)
#pragma unroll
                for (int ni = 0; ni < 4; ++ni)
                    acc[mi][ni] = __builtin_amdgcn_mfma_f32_16x16x32_bf16(af[mi], bf[ni], acc[mi][ni], 0, 0, 0);
        }
        if (ks < 3) {
            __syncthreads();   // next tile resident AND all reads of old buf done
            cur ^= 1;
        }
    }
#undef GSTAGE

    // Epilogue. D layout: row=(lane>>4)*4+r, col=lane&15 (m89).
    if (MODE == M_QKV) {
        ushort* outb = (ushort*)outp + (size_t)(y >> 1) * 16777216;
        const bool isV = (y >= 4);
        const float scale = (y < 2) ? SCQ : 1.0f;
#pragma unroll
        for (int mi = 0; mi < 4; ++mi) {
#pragma unroll
            for (int ni = 0; ni < 4; ++ni) {
                int gn = n0 + wn + ni * 16 + (lane & 15);
                if (isV) {
                    // pi^-1(s): bits[4:3]=s[3:2], bit[2]=s[4]; bits 1:0 kept
                    int s = s0 + wm + mi * 16 + (lane >> 4) * 4;
                    int p = (s & ~28) | ((s & 12) << 1) | ((s & 16) >> 2);
                    ushort4 o = make_ushort4(f2bf(acc[mi][ni][0]), f2bf(acc[mi][ni][1]),
                                             f2bf(acc[mi][ni][2]), f2bf(acc[mi][ni][3]));
                    *reinterpret_cast<ushort4*>(
                        &outb[((size_t)tblk * D_DIM + gn) * S_DIM + p]) = o;
                } else {
#pragma unroll
                    for (int r = 0; r < 4; ++r) {
                        int s = s0 + wm + mi * 16 + (lane >> 4) * 4 + r;
                        outb[(size_t)tblk * (S_DIM * D_DIM) + (size_t)s * D_DIM + gn] =
                            f2bf(acc[mi][ni][r] * scale);
                    }
                }
            }
        }
    } else {
#pragma unroll
        for (int mi = 0; mi < 4; ++mi) {
#pragma unroll
            for (int ni = 0; ni < 4; ++ni) {
                int gn = n0 + wn + ni * 16 + (lane & 15);
#pragma unroll
                for (int r = 0; r < 4; ++r) {
                    int gm = m0 + wm + mi * 16 + (lane >> 4) * 4 + r;
                    float v = acc[mi][ni][r];
                    if (MODE == M_H) {
                        v += bias[gn];
                        v = fmaxf(v, 0.f);
                        ((ushort*)outp)[(size_t)gm * D_DIM + gn] = f2bf(v);
                    } else {
                        v += bias[gn] + res[(size_t)gm * D_DIM + gn];
                        ((float*)outp)[(size_t)gm * D_DIM + gn] = v;
                    }
                }
            }
        }
    }
}

// ---------------------------------------------------------------------------
// MFMA flash attention, in-register softmax, 32 q-rows per wave (two row
// groups A/B sharing every K/V fragment load). Round-12 sync structure
// (2 buffers, __syncthreads, runtime jt loop). P = 2^S via raw v_exp_f32
// (ex2) — libm exp2f was the r11/r12 attn regression.
// Grid (x=t, y=i-chunk of 128, z=h): all blocks of one t share an XCD.
// PV A-frag lane-local via pi-permuted V^T storage. K/V staged via
// global_load_lds (linear dest + inverse-swizzled global source, rule #21).
// ---------------------------------------------------------------------------
__global__ __launch_bounds__(256) void attn_mfma(const ushort* __restrict__ qb,
                                                 const ushort* __restrict__ kb,
                                                 const ushort* __restrict__ vtb,
                                                 const float* __restrict__ x,
                                                 float* __restrict__ xt) {
    __shared__ uint4 Ks[2][512];
    __shared__ uint4 Vs[2][512];
    const int tid = threadIdx.x;
    const int lane = tid & 63;
    const int wid = tid >> 6;
    const int t = blockIdx.x;
    const int h = blockIdx.z;
    const int i0 = blockIdx.y * 128 + wid * 32;   // 32 rows per wave

    short8 qfA[2], qfB[2];
    {
        const ushort* qrowA = qb + ((size_t)t * S_DIM + i0 + (lane & 15)) * D_DIM + h * HD;
        const ushort* qrowB = qrowA + 16 * D_DIM;
#pragma unroll
        for (int kk = 0; kk < 2; ++kk) {
            qfA[kk] = *reinterpret_cast<const short8*>(qrowA + kk * 32 + (lane >> 4) * 8);
            qfB[kk] = *reinterpret_cast<const short8*>(qrowB + kk * 32 + (lane >> 4) * 8);
        }
    }

    f32x4 oaccA[4], oaccB[4];
#pragma unroll
    for (int dt = 0; dt < 4; ++dt) {
        oaccA[dt] = (f32x4){0.f, 0.f, 0.f, 0.f};
        oaccB[dt] = (f32x4){0.f, 0.f, 0.f, 0.f};
    }
    float pslA = 0.f, pslB = 0.f;

    const ushort* kbase = kb + (size_t)t * (S_DIM * D_DIM) + h * HD;
    const ushort* vbase = vtb + ((size_t)t * D_DIM + h * HD) * S_DIM;

#define STAGE(buf, j0)                                                                      \
    {                                                                                       \
        _Pragma("unroll") for (int it = 0; it < 2; ++it) {                                  \
            int slot = wid * 128 + it * 64 + lane;                                          \
            int row = slot >> 3;                                                            \
            int c = (slot & 7) ^ (row & 7);                                                 \
            __builtin_amdgcn_global_load_lds(                                               \
                (const AS1 void*)(kbase + (size_t)((j0) + row) * D_DIM + c * 8),            \
                (AS3 void*)&Ks[buf][wid * 128 + it * 64], 16, 0, 0);                        \
            __builtin_amdgcn_global_load_lds(                                               \
                (const AS1 void*)(vbase + (size_t)row * S_DIM + (j0) + c * 8),              \
                (AS3 void*)&Vs[buf][wid * 128 + it * 64], 16, 0, 0);                        \
        }                                                                                   \
    }

    STAGE(0, 0)
    __syncthreads();
    int cur = 0;

    for (int jt = 0; jt < 8; ++jt) {
        if (jt < 7) STAGE(cur ^ 1, (jt + 1) * 64)

        f32x4 saccA[4], saccB[4];
#pragma unroll
        for (int ct = 0; ct < 4; ++ct) {
            saccA[ct] = (f32x4){0.f, 0.f, 0.f, 0.f};
            saccB[ct] = (f32x4){0.f, 0.f, 0.f, 0.f};
        }
#pragma unroll
        for (int kk = 0; kk < 2; ++kk) {
#pragma unroll
            for (int ct = 0; ct < 4; ++ct) {
                int row = ct * 16 + (lane & 15);
                int c = kk * 4 + (lane >> 4);
                short8 kf = *reinterpret_cast<const short8*>(&Ks[cur][row * 8 + (c ^ (row & 7))]);
                saccA[ct] = __builtin_amdgcn_mfma_f32_16x16x32_bf16(kf, qfA[kk], saccA[ct], 0, 0, 0);
                saccB[ct] = __builtin_amdgcn_mfma_f32_16x16x32_bf16(kf, qfB[kk], saccB[ct], 0, 0, 0);
            }
        }

        // P = 2^S (Q pre-scaled); pack pairs bf16x2, all lane-local
        uint pkA[4][2], pkB[4][2];
#pragma unroll
        for (int ct = 0; ct < 4; ++ct) {
            float a0 = ex2(saccA[ct][0]);
            float a1 = ex2(saccA[ct][1]);
            float a2 = ex2(saccA[ct][2]);
            float a3 = ex2(saccA[ct][3]);
            pslA += (a0 + a1) + (a2 + a3);
            pkA[ct][0] = cvtpk(a0, a1);
            pkA[ct][1] = cvtpk(a2, a3);
            float b0 = ex2(saccB[ct][0]);
            float b1 = ex2(saccB[ct][1]);
            float b2 = ex2(saccB[ct][2]);
            float b3 = ex2(saccB[ct][3]);
            pslB += (b0 + b1) + (b2 + b3);
            pkB[ct][0] = cvtpk(b0, b1);
            pkB[ct][1] = cvtpk(b2, b3);
        }

        // O += P V : A-frags lane-local under pi; vf shared across groups
#pragma unroll
        for (int jh = 0; jh < 2; ++jh) {
            int4 pda, pdb;
            pda.x = (int)pkA[2 * jh][0];
            pda.y = (int)pkA[2 * jh][1];
            pda.z = (int)pkA[2 * jh + 1][0];
            pda.w = (int)pkA[2 * jh + 1][1];
            pdb.x = (int)pkB[2 * jh][0];
            pdb.y = (int)pkB[2 * jh][1];
            pdb.z = (int)pkB[2 * jh + 1][0];
            pdb.w = (int)pkB[2 * jh + 1][1];
            short8 pfA = *reinterpret_cast<short8*>(&pda);
            short8 pfB = *reinterpret_cast<short8*>(&pdb);
            int c = jh * 4 + (lane >> 4);
#pragma unroll
            for (int dt = 0; dt < 4; ++dt) {
                int row = dt * 16 + (lane & 15);
                short8 vf = *reinterpret_cast<const short8*>(&Vs[cur][row * 8 + (c ^ (row & 7))]);
                oaccA[dt] = __builtin_amdgcn_mfma_f32_16x16x32_bf16(pfA, vf, oaccA[dt], 0, 0, 0);
                oaccB[dt] = __builtin_amdgcn_mfma_f32_16x16x32_bf16(pfB, vf, oaccB[dt], 0, 0, 0);
            }
        }

        if (jt < 7) {
            __syncthreads();
            cur ^= 1;
        }
    }
#undef STAGE

    // Row sums: lanes {l, l^16, l^32, l^48} share row i=lane&15
    pslA += __shfl_xor(pslA, 16);
    pslA += __shfl_xor(pslA, 32);
    pslB += __shfl_xor(pslB, 16);
    pslB += __shfl_xor(pslB, 32);
    float invA = 1.0f / pslA;
    float invB = 1.0f / pslB;
    float invrA[4], invrB[4];
#pragma unroll
    for (int r = 0; r < 4; ++r) {
        int a = ((lane >> 4) * 4 + r) << 2;
        invrA[r] = __int_as_float(__builtin_amdgcn_ds_bpermute(a, __float_as_int(invA)));
        invrB[r] = __int_as_float(__builtin_amdgcn_ds_bpermute(a, __float_as_int(invB)));
    }

#pragma unroll
    for (int dt = 0; dt < 4; ++dt) {
#pragma unroll
        for (int r = 0; r < 4; ++r) {
            int srowA = i0 + (lane >> 4) * 4 + r;
            size_t oidx = (size_t)srowA * (T_DIM * D_DIM) + (size_t)t * D_DIM + h * HD + dt * 16 + (lane & 15);
            xt[oidx] = x[oidx] + oaccA[dt][r] * invrA[r];
            size_t oidxB = oidx + (size_t)16 * (T_DIM * D_DIM);
            xt[oidxB] = x[oidxB] + oaccB[dt][r] * invrB[r];
        }
    }
}

// ---------------------------------------------------------------------------
extern "C" void kernel_launch(void* const* d_in, const int* in_sizes, int n_in,
                              void* d_out, int out_size, void* d_ws, size_t ws_size,
                              hipStream_t stream) {
    const float* x  = (const float*)d_in[0];
    const float* wq = (const float*)d_in[1];
    const float* wk = (const float*)d_in[2];
    const float* wv = (const float*)d_in[3];
    const float* g1 = (const float*)d_in[4];
    const float* be1 = (const float*)d_in[5];
    const float* g2 = (const float*)d_in[6];
    const float* be2 = (const float*)d_in[7];
    const float* w1 = (const float*)d_in[8];
    const float* b1 = (const float*)d_in[9];
    const float* w2 = (const float*)d_in[10];
    const float* b2 = (const float*)d_in[11];
    float* out = (float*)d_out;

    char* ws = (char*)d_ws;
    const size_t MB = 1024ull * 1024;
    ushort* xnb = (ushort*)ws;                // 32 MB: LN1 out, later LN2 out
    ushort* qb  = (ushort*)(ws + 32 * MB);    // 32 MB: Q [T,S,D] (pre-scaled); later FFN hidden
    ushort* kb  = (ushort*)(ws + 64 * MB);    // 32 MB: K [T,S,D]
    ushort* vtb = (ushort*)(ws + 96 * MB);    // 32 MB: V^T [T,D,S] (pi-permuted s)
    ushort* wb  = (ushort*)(ws + 128 * MB);   // 5 x 64K bf16 weights (wq,wk,wv,w1,w2)
    ushort* w1b = wb + 3 * 65536;
    ushort* w2b = wb + 4 * 65536;
    ushort* hb  = qb;

    wconv<<<dim3(64, 5), 256, 0, stream>>>(wq, wk, wv, w1, w2, wb);
    ln_bf16<<<NROWS / 4, 256, 0, stream>>>(x, g1, be1, xnb);
    gemm_m97<M_QKV><<<dim3(512, 6), 256, 0, stream>>>(xnb, wb, nullptr, nullptr, qb);
    attn_mfma<<<dim3(T_DIM, S_DIM / 128, 4), 256, 0, stream>>>(qb, kb, vtb, x, out);
    ln_bf16<<<NROWS / 4, 256, 0, stream>>>(out, g2, be2, xnb);
    gemm_m97<M_H><<<dim3(512, 2), 256, 0, stream>>>(xnb, w1b, b1, nullptr, hb);
    gemm_m97<M_FFN2><<<dim3(512, 2), 256, 0, stream>>>(hb, w2b, b2, out, out);
}